// Round 16
// baseline (150.186 us; speedup 1.0000x reference)
//
#include <hip/hip_runtime.h>
#include <hip/hip_bf16.h>
#include <cstdint>
#include <cstddef>

typedef __bf16 bf16_t;
typedef __bf16 bf16x8 __attribute__((ext_vector_type(8)));
typedef __bf16 bf16x4 __attribute__((ext_vector_type(4)));
typedef float f32x4 __attribute__((ext_vector_type(4)));

#define DEVINL __device__ __forceinline__

DEVINL void gload_lds16(const bf16_t* g, bf16_t* l) {
  __builtin_amdgcn_global_load_lds(
      (__attribute__((address_space(1))) void*)(g),
      (__attribute__((address_space(3))) void*)(l), 16, 0, 0);
}

// ---------------------------------------------------------------------------
// prep: ONE dispatch fusing
//   blocks [0,2048):    x fp32 -> xb bf16 (8M elems, lane-consecutive f4)
//   blocks [2048,2816): W [1024][3072] -> Wt [3072][1024] bf16 (LDS tiled);
//                       first 32 of these also zero Rsum[8192]
// ---------------------------------------------------------------------------
__global__ __launch_bounds__(256) void prep(
    const float* __restrict__ x, bf16_t* __restrict__ xb,
    const float* __restrict__ W, bf16_t* __restrict__ Wt,
    float* __restrict__ Rsum) {
  __shared__ bf16_t tile[64][66];
  const int tid = threadIdx.x;
  if (blockIdx.x < 2048) {
    const long base = (long)blockIdx.x * 4096;
#pragma unroll
    for (int k = 0; k < 4; ++k) {
      const long i = base + k * 1024 + tid * 4;
      float4 v = *reinterpret_cast<const float4*>(x + i);
      bf16x4 o = { (bf16_t)v.x, (bf16_t)v.y, (bf16_t)v.z, (bf16_t)v.w };
      *reinterpret_cast<bf16x4*>(xb + i) = o;
    }
  } else {
    const int b2 = blockIdx.x - 2048;  // 0..767
    if (b2 < 32) Rsum[b2 * 256 + tid] = 0.f;
    const int c0 = (b2 % 48) * 64, r0 = (b2 / 48) * 64;
    const int tc = tid & 63, tr = tid >> 6;
#pragma unroll
    for (int k = 0; k < 16; ++k) {
      int rl = k * 4 + tr;
      tile[rl][tc] = (bf16_t)W[(size_t)(r0 + rl) * 3072 + c0 + tc];
    }
    __syncthreads();
#pragma unroll
    for (int k = 0; k < 16; ++k) {
      int cl = k * 4 + tr;
      Wt[(size_t)(c0 + cl) * 1024 + r0 + tc] = tile[tc][cl];
    }
  }
}

// ---------------------------------------------------------------------------
// gemm128 BK=64, 512 threads / 8 waves (SINGLE-VARIABLE change vs R15's
// 256-thr best: same tile 128x128, same 2-slot dbuf, same 1-ahead staging,
// same LKW+VMW(0)+BAR phase, same row-XOR swizzle, same band raster).
// Wave grid 2M x 4N, wave-tile 64x32 (acc 32 VGPR) -> 2 blocks/CU now give
// 4 waves/SIMD (was 2): doubles the TLP pool hiding the per-phase drain.
// EPI 0: Q|K dense bf16 (Q scaled 1/32, +bias); seg 2 writes V transposed.
// EPI 2: E = exp(acc) bf16 + per-row sums -> atomicAdd Rsum (max-free).
// EPI 1: fp32 out scaled by 1/Rsum[row].
// ---------------------------------------------------------------------------
template <int EPI, int NQ>
__global__ __launch_bounds__(512, 4) void gemm128(
    const bf16_t* __restrict__ A, const bf16_t* __restrict__ B,
    void* __restrict__ C, const float* __restrict__ bias,
    int lda, int ldb, int ldc, long sA, long sB, long sC,
    bf16_t* __restrict__ VtOut, float* __restrict__ Rsum) {
  __shared__ bf16_t lds[2][256 * 64];  // slot: A 128x64 | B 128x64

  constexpr int GM = 8;
  const int gx = gridDim.x, gy = gridDim.y;
  const int nwg = gx * gy * gridDim.z;
  const int flat = blockIdx.x + gx * (blockIdx.y + gy * blockIdx.z);
  const int v = (flat & 7) * (nwg >> 3) + (flat >> 3);
  const int slice = gx * gy;
  const int bz = v / slice;
  const int rr = v % slice;
  const int BS = GM * gx;
  const int band = rr / BS, tt = rr % BS;
  const int bx = tt / GM;
  const int by = band * GM + (tt % GM);

  const int m0 = by * 128, n0 = bx * 128;
  A += (size_t)bz * sA;
  B += (size_t)bz * sB;

  const int tid = threadIdx.x;
  const int w = tid >> 6, lane = tid & 63;
  const int wr = w >> 2, wc = w & 3;  // 2M x 4N

  // staging: each wave stages 16 A rows + 16 B rows (2+2 gloads/thread);
  // lane -> row = lane>>3, chunk = (lane&7)^(lane>>3)  (T2 pre-swizzle)
  const int srow = lane >> 3;
  const int schunk = ((lane & 7) ^ (lane >> 3)) * 8;
  const bf16_t* gA = A + (size_t)(m0 + w * 16 + srow) * lda + schunk;
  const bf16_t* gB = B + (size_t)(n0 + w * 16 + srow) * ldb + schunk;

  const int rsel = lane & 15, kg = lane >> 4;
  // read-side phys-slot offsets (elements): ((ks*4+kg)^(rsel&7))*8
  const int ksw0 = ((kg) ^ (rsel & 7)) * 8;
  const int ksw1 = ((4 + kg) ^ (rsel & 7)) * 8;
  f32x4 acc[4][2] = {};

#define SA(S, q)                                                              \
  _Pragma("unroll") for (int p = 0; p < 2; ++p)                               \
      gload_lds16(gA + (size_t)(q) * 64 + (size_t)(p * 8) * lda,              \
                  &lds[S][(w * 16 + p * 8) * 64]);
#define SB(S, q)                                                              \
  _Pragma("unroll") for (int p = 0; p < 2; ++p)                               \
      gload_lds16(gB + (size_t)(q) * 64 + (size_t)(p * 8) * ldb,              \
                  &lds[S][128 * 64 + (w * 16 + p * 8) * 64]);
#define VMW(N) asm volatile("s_waitcnt vmcnt(%0)" ::"n"(N) : "memory")
#define LKW asm volatile("s_waitcnt lgkmcnt(0)" ::: "memory")
#define BAR __builtin_amdgcn_s_barrier()

  SA(0, 0); SB(0, 0);
  VMW(0);
  BAR;

#pragma unroll
  for (int q = 0; q < NQ; ++q) {
    const int s = q & 1;
    if (q + 1 < NQ) {
      SA(s ^ 1, q + 1);
      SB(s ^ 1, q + 1);
    }
    bf16x8 af[4][2], bfr[2][2];
#pragma unroll
    for (int j = 0; j < 2; ++j) {
      const int rowb = 128 * 64 + (wc * 32 + j * 16 + rsel) * 64;
      bfr[j][0] = *reinterpret_cast<const bf16x8*>(&lds[s][rowb + ksw0]);
      bfr[j][1] = *reinterpret_cast<const bf16x8*>(&lds[s][rowb + ksw1]);
    }
#pragma unroll
    for (int i = 0; i < 4; ++i) {
      const int rowa = (wr * 64 + i * 16 + rsel) * 64;
      af[i][0] = *reinterpret_cast<const bf16x8*>(&lds[s][rowa + ksw0]);
      af[i][1] = *reinterpret_cast<const bf16x8*>(&lds[s][rowa + ksw1]);
    }
    __builtin_amdgcn_s_setprio(1);
#pragma unroll
    for (int ks = 0; ks < 2; ++ks)
#pragma unroll
      for (int i = 0; i < 4; ++i)
#pragma unroll
        for (int j = 0; j < 2; ++j)
          acc[i][j] = __builtin_amdgcn_mfma_f32_16x16x32_bf16(
              af[i][ks], bfr[j][ks], acc[i][j], 0, 0, 0);
    __builtin_amdgcn_s_setprio(0);
    if (q + 1 < NQ) {
      LKW;     // slot-s frag reads retired (WAR vs next phase's staging)
      VMW(0);  // tile q+1 landed -> visible to all after BAR
      BAR;
    }
  }
#undef SA
#undef SB
#undef VMW
#undef LKW
#undef BAR

  // epilogue: C/D layout col=lane&15, row=(lane>>4)*4+reg (m89-verified)
  const int rb = (lane >> 4) * 4, cs = lane & 15;
  if constexpr (EPI == 0) {
    const int seg = n0 >> 10;
    if (seg < 2) {
      bf16_t* Cb = (bf16_t*)C + (size_t)seg * 8192 * 1024;
      const float scl = (seg == 0) ? 0.03125f : 1.0f;
#pragma unroll
      for (int i = 0; i < 4; ++i)
#pragma unroll
        for (int j = 0; j < 2; ++j)
#pragma unroll
          for (int r = 0; r < 4; ++r) {
            const int row = m0 + wr * 64 + i * 16 + rb + r;
            const int col = n0 + wc * 32 + j * 16 + cs;
            Cb[(size_t)row * 1024 + (col & 1023)] =
                (bf16_t)((acc[i][j][r] + bias[col]) * scl);
          }
    } else {
      // V transposed: Vt[b][h][n], 4 consecutive n per (i,j)
      const int bq = m0 >> 11;
#pragma unroll
      for (int i = 0; i < 4; ++i) {
        const int nloc = (m0 & 2047) + wr * 64 + i * 16 + rb;
#pragma unroll
        for (int j = 0; j < 2; ++j) {
          const int col = n0 + wc * 32 + j * 16 + cs;
          const int h = col & 1023;
          const float bv = bias[col];
          bf16x4 pk;
#pragma unroll
          for (int r = 0; r < 4; ++r) pk[r] = (bf16_t)(acc[i][j][r] + bv);
          *reinterpret_cast<bf16x4*>(
              VtOut + ((size_t)bq * 1024 + h) * 2048 + nloc) = pk;
        }
      }
    }
  } else if constexpr (EPI == 2) {
    // E = exp(acc) bf16 + per-row partial sums -> Rsum (device atomics)
    bf16_t* Cb = (bf16_t*)C;
    float rsum[4][4];  // [i][r]
#pragma unroll
    for (int i = 0; i < 4; ++i)
#pragma unroll
      for (int r = 0; r < 4; ++r) rsum[i][r] = 0.f;
#pragma unroll
    for (int i = 0; i < 4; ++i)
#pragma unroll
      for (int j = 0; j < 2; ++j)
#pragma unroll
        for (int r = 0; r < 4; ++r) {
          const int row = m0 + wr * 64 + i * 16 + rb + r;
          const int col = n0 + wc * 32 + j * 16 + cs;
          const float e = __expf(acc[i][j][r]);
          Cb[(size_t)bz * sC + (size_t)row * ldc + col] = (bf16_t)e;
          rsum[i][r] += e;
        }
#pragma unroll
    for (int off = 1; off < 16; off <<= 1)
#pragma unroll
      for (int i = 0; i < 4; ++i)
#pragma unroll
        for (int r = 0; r < 4; ++r)
          rsum[i][r] += __shfl_xor(rsum[i][r], off);
    if ((lane & 15) == 0) {
#pragma unroll
      for (int i = 0; i < 4; ++i)
#pragma unroll
        for (int r = 0; r < 4; ++r)
          atomicAdd(&Rsum[bz * 2048 + m0 + wr * 64 + i * 16 + rb + r],
                    rsum[i][r]);
    }
  } else {
    // fp32 out, normalized by 1/Rsum[row]
    float* Ob = (float*)C + (size_t)bz * sC;
#pragma unroll
    for (int i = 0; i < 4; ++i) {
#pragma unroll
      for (int r = 0; r < 4; ++r) {
        const int row = m0 + wr * 64 + i * 16 + rb + r;
        const float inv = 1.0f / Rsum[bz * 2048 + row];
#pragma unroll
        for (int j = 0; j < 2; ++j) {
          const int col = n0 + wc * 32 + j * 16 + cs;
          Ob[(size_t)row * ldc + col] = acc[i][j][r] * inv;
        }
      }
    }
  }
}

// ---------------------------------------------------------------------------
// launch
// ---------------------------------------------------------------------------
extern "C" void kernel_launch(void* const* d_in, const int* in_sizes, int n_in,
                              void* d_out, int out_size, void* d_ws,
                              size_t ws_size, hipStream_t stream) {
  const float* x = (const float*)d_in[0];  // [4,2048,1024]
  const float* W = (const float*)d_in[1];  // [1024,3072]
  const float* b = (const float*)d_in[2];  // [3072]
  float* out = (float*)d_out;              // [4,2048,1024] fp32

  char* w = (char*)d_ws;
  bf16_t* xb = (bf16_t*)w;   w += (size_t)8192 * 1024 * 2;
  bf16_t* Wt = (bf16_t*)w;   w += (size_t)3072 * 1024 * 2;
  bf16_t* QKV = (bf16_t*)w;  w += (size_t)2 * 8192 * 1024 * 2;  // Q,K dense
  bf16_t* Vt = (bf16_t*)w;   w += (size_t)4 * 1024 * 2048 * 2;
  bf16_t* E = (bf16_t*)w;    w += (size_t)4 * 2048 * 2048 * 2;  // exp(S)
  float* Rsum = (float*)w;   w += (size_t)8192 * 4;

  bf16_t* Q = QKV;
  bf16_t* Kd = QKV + (size_t)8192 * 1024;

  // fused: cast x->bf16 (2048 blocks) | transpose W + zero Rsum (768 blocks)
  prep<<<2816, 256, 0, stream>>>(x, xb, W, Wt, Rsum);

  // Q|K dense + V transposed into Vt. grid 24x64 = 1536 blocks, 16 phases
  gemm128<0, 16><<<dim3(24, 64, 1), 512, 0, stream>>>(
      xb, Wt, QKV, b, 1024, 1024, 1024, 0, 0, 0, Vt, nullptr);

  // E = exp(Qs @ K^T) bf16 + row sums. grid 16x16x4 = 1024 blocks, 16 phases
  gemm128<2, 16><<<dim3(16, 16, 4), 512, 0, stream>>>(
      Q, Kd, E, nullptr, 1024, 1024, 2048,
      (long)2048 * 1024, (long)2048 * 1024, (long)2048 * 2048,
      nullptr, Rsum);

  // out = (E @ Vt^T) / Rsum[row], fp32. grid 8x16x4 = 512 blocks, 32 phases
  gemm128<1, 32><<<dim3(8, 16, 4), 512, 0, stream>>>(
      E, Vt, out, nullptr, 2048, 2048, 1024,
      (long)2048 * 2048, (long)1024 * 2048, (long)2048 * 1024,
      nullptr, Rsum);
}

// Round 17
// 143.898 us; speedup vs baseline: 1.0437x; 1.0437x over previous
//
#include <hip/hip_runtime.h>
#include <hip/hip_bf16.h>
#include <cstdint>
#include <cstddef>

typedef __bf16 bf16_t;
typedef __bf16 bf16x8 __attribute__((ext_vector_type(8)));
typedef __bf16 bf16x4 __attribute__((ext_vector_type(4)));
typedef float f32x4 __attribute__((ext_vector_type(4)));

#define DEVINL __device__ __forceinline__

DEVINL void gload_lds16(const bf16_t* g, bf16_t* l) {
  __builtin_amdgcn_global_load_lds(
      (__attribute__((address_space(1))) void*)(g),
      (__attribute__((address_space(3))) void*)(l), 16, 0, 0);
}

// ---------------------------------------------------------------------------
// prep: ONE dispatch fusing
//   blocks [0,2048):    x fp32 -> xb bf16 (8M elems, lane-consecutive f4)
//   blocks [2048,2816): W [1024][3072] -> Wt [3072][1024] bf16 (LDS tiled);
//                       first 32 of these also zero Rsum[8192]
// ---------------------------------------------------------------------------
__global__ __launch_bounds__(256) void prep(
    const float* __restrict__ x, bf16_t* __restrict__ xb,
    const float* __restrict__ W, bf16_t* __restrict__ Wt,
    float* __restrict__ Rsum) {
  __shared__ bf16_t tile[64][66];
  const int tid = threadIdx.x;
  if (blockIdx.x < 2048) {
    const long base = (long)blockIdx.x * 4096;
#pragma unroll
    for (int k = 0; k < 4; ++k) {
      const long i = base + k * 1024 + tid * 4;
      float4 v = *reinterpret_cast<const float4*>(x + i);
      bf16x4 o = { (bf16_t)v.x, (bf16_t)v.y, (bf16_t)v.z, (bf16_t)v.w };
      *reinterpret_cast<bf16x4*>(xb + i) = o;
    }
  } else {
    const int b2 = blockIdx.x - 2048;  // 0..767
    if (b2 < 32) Rsum[b2 * 256 + tid] = 0.f;
    const int c0 = (b2 % 48) * 64, r0 = (b2 / 48) * 64;
    const int tc = tid & 63, tr = tid >> 6;
#pragma unroll
    for (int k = 0; k < 16; ++k) {
      int rl = k * 4 + tr;
      tile[rl][tc] = (bf16_t)W[(size_t)(r0 + rl) * 3072 + c0 + tc];
    }
    __syncthreads();
#pragma unroll
    for (int k = 0; k < 16; ++k) {
      int cl = k * 4 + tr;
      Wt[(size_t)(c0 + cl) * 1024 + r0 + tc] = tile[tc][cl];
    }
  }
}

// ---------------------------------------------------------------------------
// gemmA: 512-thread / 8-wave variant (R16 core — measured 55.0 us on G1).
// 128x128 tile, BK=64, 2 LDS slots, 1-ahead staging, LKW+VMW(0)+BAR phase,
// row-XOR swizzle (verified 0-conflict), band raster. Wave grid 2M x 4N.
// EPI 0 only: Q|K dense bf16 (Q scaled 1/32, +bias); seg 2 writes V
// transposed into VtOut[b][h][n].
// ---------------------------------------------------------------------------
template <int NQ>
__global__ __launch_bounds__(512, 4) void gemmA(
    const bf16_t* __restrict__ A, const bf16_t* __restrict__ B,
    void* __restrict__ C, const float* __restrict__ bias,
    int lda, int ldb, bf16_t* __restrict__ VtOut) {
  __shared__ bf16_t lds[2][256 * 64];

  constexpr int GM = 8;
  const int gx = gridDim.x, gy = gridDim.y;
  const int nwg = gx * gy;
  const int flat = blockIdx.x + gx * blockIdx.y;
  const int v = (flat & 7) * (nwg >> 3) + (flat >> 3);
  const int BS = GM * gx;
  const int band = v / BS, tt = v % BS;
  const int bx = tt / GM;
  const int by = band * GM + (tt % GM);

  const int m0 = by * 128, n0 = bx * 128;

  const int tid = threadIdx.x;
  const int w = tid >> 6, lane = tid & 63;
  const int wr = w >> 2, wc = w & 3;  // 2M x 4N

  const int srow = lane >> 3;
  const int schunk = ((lane & 7) ^ (lane >> 3)) * 8;
  const bf16_t* gA = A + (size_t)(m0 + w * 16 + srow) * lda + schunk;
  const bf16_t* gB = B + (size_t)(n0 + w * 16 + srow) * ldb + schunk;

  const int rsel = lane & 15, kg = lane >> 4;
  const int ksw0 = ((kg) ^ (rsel & 7)) * 8;
  const int ksw1 = ((4 + kg) ^ (rsel & 7)) * 8;
  f32x4 acc[4][2] = {};

#define SA(S, q)                                                              \
  _Pragma("unroll") for (int p = 0; p < 2; ++p)                               \
      gload_lds16(gA + (size_t)(q) * 64 + (size_t)(p * 8) * lda,              \
                  &lds[S][(w * 16 + p * 8) * 64]);
#define SB(S, q)                                                              \
  _Pragma("unroll") for (int p = 0; p < 2; ++p)                               \
      gload_lds16(gB + (size_t)(q) * 64 + (size_t)(p * 8) * ldb,              \
                  &lds[S][128 * 64 + (w * 16 + p * 8) * 64]);
#define VMW(N) asm volatile("s_waitcnt vmcnt(%0)" ::"n"(N) : "memory")
#define LKW asm volatile("s_waitcnt lgkmcnt(0)" ::: "memory")
#define BAR __builtin_amdgcn_s_barrier()

  SA(0, 0); SB(0, 0);
  VMW(0);
  BAR;

#pragma unroll
  for (int q = 0; q < NQ; ++q) {
    const int s = q & 1;
    if (q + 1 < NQ) {
      SA(s ^ 1, q + 1);
      SB(s ^ 1, q + 1);
    }
    bf16x8 af[4][2], bfr[2][2];
#pragma unroll
    for (int j = 0; j < 2; ++j) {
      const int rowb = 128 * 64 + (wc * 32 + j * 16 + rsel) * 64;
      bfr[j][0] = *reinterpret_cast<const bf16x8*>(&lds[s][rowb + ksw0]);
      bfr[j][1] = *reinterpret_cast<const bf16x8*>(&lds[s][rowb + ksw1]);
    }
#pragma unroll
    for (int i = 0; i < 4; ++i) {
      const int rowa = (wr * 64 + i * 16 + rsel) * 64;
      af[i][0] = *reinterpret_cast<const bf16x8*>(&lds[s][rowa + ksw0]);
      af[i][1] = *reinterpret_cast<const bf16x8*>(&lds[s][rowa + ksw1]);
    }
    __builtin_amdgcn_s_setprio(1);
#pragma unroll
    for (int ks = 0; ks < 2; ++ks)
#pragma unroll
      for (int i = 0; i < 4; ++i)
#pragma unroll
        for (int j = 0; j < 2; ++j)
          acc[i][j] = __builtin_amdgcn_mfma_f32_16x16x32_bf16(
              af[i][ks], bfr[j][ks], acc[i][j], 0, 0, 0);
    __builtin_amdgcn_s_setprio(0);
    if (q + 1 < NQ) {
      LKW;
      VMW(0);
      BAR;
    }
  }
#undef SA
#undef SB
#undef VMW
#undef LKW
#undef BAR

  const int rb = (lane >> 4) * 4, cs = lane & 15;
  const int seg = n0 >> 10;
  if (seg < 2) {
    bf16_t* Cb = (bf16_t*)C + (size_t)seg * 8192 * 1024;
    const float scl = (seg == 0) ? 0.03125f : 1.0f;
#pragma unroll
    for (int i = 0; i < 4; ++i)
#pragma unroll
      for (int j = 0; j < 2; ++j)
#pragma unroll
        for (int r = 0; r < 4; ++r) {
          const int row = m0 + wr * 64 + i * 16 + rb + r;
          const int col = n0 + wc * 32 + j * 16 + cs;
          Cb[(size_t)row * 1024 + (col & 1023)] =
              (bf16_t)((acc[i][j][r] + bias[col]) * scl);
        }
  } else {
    const int bq = m0 >> 11;
#pragma unroll
    for (int i = 0; i < 4; ++i) {
      const int nloc = (m0 & 2047) + wr * 64 + i * 16 + rb;
#pragma unroll
      for (int j = 0; j < 2; ++j) {
        const int col = n0 + wc * 32 + j * 16 + cs;
        const int h = col & 1023;
        const float bv = bias[col];
        bf16x4 pk;
#pragma unroll
        for (int r = 0; r < 4; ++r) pk[r] = (bf16_t)(acc[i][j][r] + bv);
        *reinterpret_cast<bf16x4*>(
            VtOut + ((size_t)bq * 1024 + h) * 2048 + nloc) = pk;
      }
    }
  }
}

// ---------------------------------------------------------------------------
// gemmB: 256-thread / 4-wave variant (R15 core — measured best for G2/G3).
// 128x128 tile, BK=64, 2 LDS slots (64 KB -> 2 blocks/CU), 1-ahead staging,
// LKW+VMW(0)+BAR phase, row-XOR swizzle, band raster. Wave grid 2M x 2N.
// EPI 2: E = exp(acc) bf16 + per-row sums -> atomicAdd Rsum (max-free).
// EPI 1: fp32 out scaled by 1/Rsum[row].
// ---------------------------------------------------------------------------
template <int EPI, int NQ>
__global__ __launch_bounds__(256, 2) void gemmB(
    const bf16_t* __restrict__ A, const bf16_t* __restrict__ B,
    void* __restrict__ C, int lda, int ldb, int ldc,
    long sA, long sB, long sC, float* __restrict__ Rsum) {
  __shared__ bf16_t lds[2][256 * 64];

  constexpr int GM = 8;
  const int gx = gridDim.x, gy = gridDim.y;
  const int nwg = gx * gy * gridDim.z;
  const int flat = blockIdx.x + gx * (blockIdx.y + gy * blockIdx.z);
  const int v = (flat & 7) * (nwg >> 3) + (flat >> 3);
  const int slice = gx * gy;
  const int bz = v / slice;
  const int rr = v % slice;
  const int BS = GM * gx;
  const int band = rr / BS, tt = rr % BS;
  const int bx = tt / GM;
  const int by = band * GM + (tt % GM);

  const int m0 = by * 128, n0 = bx * 128;
  A += (size_t)bz * sA;
  B += (size_t)bz * sB;

  const int tid = threadIdx.x;
  const int w = tid >> 6, lane = tid & 63;
  const int wr = w >> 1, wc = w & 1;

  const int srow = lane >> 3;
  const int schunk = ((lane & 7) ^ (lane >> 3)) * 8;
  const bf16_t* gA = A + (size_t)(m0 + w * 32 + srow) * lda + schunk;
  const bf16_t* gB = B + (size_t)(n0 + w * 32 + srow) * ldb + schunk;

  const int rsel = lane & 15, kg = lane >> 4;
  const int ksw0 = ((kg) ^ (rsel & 7)) * 8;
  const int ksw1 = ((4 + kg) ^ (rsel & 7)) * 8;
  f32x4 acc[4][4] = {};

#define SA(S, q)                                                              \
  _Pragma("unroll") for (int p = 0; p < 4; ++p)                               \
      gload_lds16(gA + (size_t)(q) * 64 + (size_t)(p * 8) * lda,              \
                  &lds[S][(w * 32 + p * 8) * 64]);
#define SB(S, q)                                                              \
  _Pragma("unroll") for (int p = 0; p < 4; ++p)                               \
      gload_lds16(gB + (size_t)(q) * 64 + (size_t)(p * 8) * ldb,              \
                  &lds[S][128 * 64 + (w * 32 + p * 8) * 64]);
#define VMW(N) asm volatile("s_waitcnt vmcnt(%0)" ::"n"(N) : "memory")
#define LKW asm volatile("s_waitcnt lgkmcnt(0)" ::: "memory")
#define BAR __builtin_amdgcn_s_barrier()

  SA(0, 0); SB(0, 0);
  VMW(0);
  BAR;

#pragma unroll
  for (int q = 0; q < NQ; ++q) {
    const int s = q & 1;
    if (q + 1 < NQ) {
      SA(s ^ 1, q + 1);
      SB(s ^ 1, q + 1);
    }
    bf16x8 af[4][2], bfr[4][2];
#pragma unroll
    for (int j = 0; j < 4; ++j) {
      const int rowb = 128 * 64 + (wc * 64 + j * 16 + rsel) * 64;
      bfr[j][0] = *reinterpret_cast<const bf16x8*>(&lds[s][rowb + ksw0]);
      bfr[j][1] = *reinterpret_cast<const bf16x8*>(&lds[s][rowb + ksw1]);
    }
#pragma unroll
    for (int i = 0; i < 4; ++i) {
      const int rowa = (wr * 64 + i * 16 + rsel) * 64;
      af[i][0] = *reinterpret_cast<const bf16x8*>(&lds[s][rowa + ksw0]);
      af[i][1] = *reinterpret_cast<const bf16x8*>(&lds[s][rowa + ksw1]);
    }
    __builtin_amdgcn_s_setprio(1);
#pragma unroll
    for (int ks = 0; ks < 2; ++ks)
#pragma unroll
      for (int i = 0; i < 4; ++i)
#pragma unroll
        for (int j = 0; j < 4; ++j)
          acc[i][j] = __builtin_amdgcn_mfma_f32_16x16x32_bf16(
              af[i][ks], bfr[j][ks], acc[i][j], 0, 0, 0);
    __builtin_amdgcn_s_setprio(0);
    if (q + 1 < NQ) {
      LKW;
      VMW(0);
      BAR;
    }
  }
#undef SA
#undef SB
#undef VMW
#undef LKW
#undef BAR

  const int rb = (lane >> 4) * 4, cs = lane & 15;
  if constexpr (EPI == 2) {
    bf16_t* Cb = (bf16_t*)C;
    float rsum[4][4];
#pragma unroll
    for (int i = 0; i < 4; ++i)
#pragma unroll
      for (int r = 0; r < 4; ++r) rsum[i][r] = 0.f;
#pragma unroll
    for (int i = 0; i < 4; ++i)
#pragma unroll
      for (int j = 0; j < 4; ++j)
#pragma unroll
        for (int r = 0; r < 4; ++r) {
          const int row = m0 + wr * 64 + i * 16 + rb + r;
          const int col = n0 + wc * 64 + j * 16 + cs;
          const float e = __expf(acc[i][j][r]);
          Cb[(size_t)bz * sC + (size_t)row * ldc + col] = (bf16_t)e;
          rsum[i][r] += e;
        }
#pragma unroll
    for (int off = 1; off < 16; off <<= 1)
#pragma unroll
      for (int i = 0; i < 4; ++i)
#pragma unroll
        for (int r = 0; r < 4; ++r)
          rsum[i][r] += __shfl_xor(rsum[i][r], off);
    if ((lane & 15) == 0) {
#pragma unroll
      for (int i = 0; i < 4; ++i)
#pragma unroll
        for (int r = 0; r < 4; ++r)
          atomicAdd(&Rsum[bz * 2048 + m0 + wr * 64 + i * 16 + rb + r],
                    rsum[i][r]);
    }
  } else {
    float* Ob = (float*)C + (size_t)bz * sC;
#pragma unroll
    for (int i = 0; i < 4; ++i) {
#pragma unroll
      for (int r = 0; r < 4; ++r) {
        const int row = m0 + wr * 64 + i * 16 + rb + r;
        const float inv = 1.0f / Rsum[bz * 2048 + row];
#pragma unroll
        for (int j = 0; j < 4; ++j) {
          const int col = n0 + wc * 64 + j * 16 + cs;
          Ob[(size_t)row * ldc + col] = acc[i][j][r] * inv;
        }
      }
    }
  }
}

// ---------------------------------------------------------------------------
// launch
// ---------------------------------------------------------------------------
extern "C" void kernel_launch(void* const* d_in, const int* in_sizes, int n_in,
                              void* d_out, int out_size, void* d_ws,
                              size_t ws_size, hipStream_t stream) {
  const float* x = (const float*)d_in[0];  // [4,2048,1024]
  const float* W = (const float*)d_in[1];  // [1024,3072]
  const float* b = (const float*)d_in[2];  // [3072]
  float* out = (float*)d_out;              // [4,2048,1024] fp32

  char* w = (char*)d_ws;
  bf16_t* xb = (bf16_t*)w;   w += (size_t)8192 * 1024 * 2;
  bf16_t* Wt = (bf16_t*)w;   w += (size_t)3072 * 1024 * 2;
  bf16_t* QKV = (bf16_t*)w;  w += (size_t)2 * 8192 * 1024 * 2;  // Q,K dense
  bf16_t* Vt = (bf16_t*)w;   w += (size_t)4 * 1024 * 2048 * 2;
  bf16_t* E = (bf16_t*)w;    w += (size_t)4 * 2048 * 2048 * 2;  // exp(S)
  float* Rsum = (float*)w;   w += (size_t)8192 * 4;

  bf16_t* Q = QKV;
  bf16_t* Kd = QKV + (size_t)8192 * 1024;

  // fused: cast x->bf16 (2048 blocks) | transpose W + zero Rsum (768 blocks)
  prep<<<2816, 256, 0, stream>>>(x, xb, W, Wt, Rsum);

  // Q|K dense + V transposed into Vt. 512-thr variant (measured 55.0 us)
  gemmA<16><<<dim3(24, 64), 512, 0, stream>>>(
      xb, Wt, QKV, b, 1024, 1024, Vt);

  // E = exp(Qs @ K^T) bf16 + row sums. 256-thr variant
  gemmB<2, 16><<<dim3(16, 16, 4), 256, 0, stream>>>(
      Q, Kd, E, 1024, 1024, 2048,
      (long)2048 * 1024, (long)2048 * 1024, (long)2048 * 2048, Rsum);

  // out = (E @ Vt^T) / Rsum[row], fp32. 256-thr variant
  gemmB<1, 32><<<dim3(8, 16, 4), 256, 0, stream>>>(
      E, Vt, out, 2048, 2048, 1024,
      (long)2048 * 2048, (long)1024 * 2048, (long)2048 * 1024, Rsum);
}